// Round 8
// baseline (128.547 us; speedup 1.0000x reference)
//
#include <hip/hip_runtime.h>
#include <hip/hip_bf16.h>

#define B_ROWS 4096
#define T_LEN  8192
#define N_TAPS 256

typedef __attribute__((ext_vector_type(8))) short short8;
typedef __attribute__((ext_vector_type(4))) short short4v;
typedef __attribute__((ext_vector_type(4))) float f32x4;

__device__ inline ushort f2bf(float f) {
    __hip_bfloat16 h = __float2bfloat16(f);
    union { __hip_bfloat16 h; ushort u; } c;
    c.h = h;
    return c.u;
}

// async global->LDS, 16 B per lane. LDS dest = wave-uniform base + lane*16.
typedef __attribute__((address_space(1))) const void g_void;
typedef __attribute__((address_space(3))) void s_void;
__device__ inline void gload16(const void* g, void* s) {
    __builtin_amdgcn_global_load_lds((g_void*)g, (s_void*)s, 16, 0, 0);
}

// ---------------------------------------------------------------------------
// Phase 0a: cast z (256 x 8192 fp32) -> zbf (bf16)
// ---------------------------------------------------------------------------
__global__ __launch_bounds__(256) void fir_cast_z(const float* __restrict__ z,
                                                  ushort* __restrict__ zbf) {
    const int idx = (blockIdx.x * 256 + threadIdx.x) * 8;
    float4 a = *(const float4*)&z[idx];
    float4 b = *(const float4*)&z[idx + 4];
    short8 o;
    o[0] = (short)f2bf(a.x); o[1] = (short)f2bf(a.y);
    o[2] = (short)f2bf(a.z); o[3] = (short)f2bf(a.w);
    o[4] = (short)f2bf(b.x); o[5] = (short)f2bf(b.y);
    o[6] = (short)f2bf(b.z); o[7] = (short)f2bf(b.w);
    *(short8*)&zbf[idx] = o;
}

// ---------------------------------------------------------------------------
// Phase 0b: Toeplitz B-fragment table (unchanged, verified R3)
// ---------------------------------------------------------------------------
__global__ void fir_build_wtab(const float* __restrict__ b,
                               ushort* __restrict__ wtab) {
    const int a = blockIdx.x;        // 0..21
    const int lane = threadIdx.x;    // 0..63
    const int l15 = lane & 15, lg = lane >> 4;
    short8 o;
    #pragma unroll
    for (int j = 0; j < 8; ++j) {
        const int bi = 16 * a - 32 + l15 - lg * 8 - j;
        const float v = (bi >= 0 && bi < N_TAPS) ? b[bi] : 0.f;
        o[j] = (short)f2bf(v);
    }
    *(short8*)&wtab[(a * 64 + lane) * 8] = o;
}

// ---------------------------------------------------------------------------
// Phase 1: zi GEMM — DRAM-pattern fix.
// R4/R5/R7 (3 different pipelines) all ran ~82 µs: x read as 256 B/row x 64
// strided rows/iter -> ~1.6 TB/s effective (DRAM row thrash). The conv reads
// the same x at ~6 TB/s with contiguous ~KB/row staging. Fix: A staged in
// SUPER-tiles of 64 rows x 256 fp32 (64 KB), ONE gload_lds wave-instr per
// row = 1 KB contiguous per row, refreshed every 4 inner iters.
// B: 32 KB per inner iter via gload_lds (L2-resident slice), R7 pattern.
// Pre-swizzled sources <-> XOR reads (involution verified R4-R7).
// ---------------------------------------------------------------------------
#define MT 64
#define SUPK 256    // fp32 cols per A super-tile
#define GBK 64      // k per inner iter

__global__ __launch_bounds__(512, 2) void fir_zi_gemm(
        const float* __restrict__ x,
        const ushort* __restrict__ zbf,
        float* __restrict__ part,
        int kslices) {
    __shared__ float  Asf[MT * SUPK];     // 64 KB (64 rows x 1 KB)
    __shared__ ushort Bs[N_TAPS * GBK];   // 32 KB (256 rows x 128 B)
    const int i0 = blockIdx.x * MT;
    const int ks = blockIdx.y;
    const int klen = T_LEN / kslices;     // 1024
    const int kbase = ks * klen;
    const int tid = threadIdx.x;
    const int wid = tid >> 6;             // 0..7
    const int lane = tid & 63;
    const int wm = wid >> 2, wn = wid & 3;
    const int l15 = lane & 15, lg = lane >> 4;

    f32x4 acc[2][4];
    #pragma unroll
    for (int mi = 0; mi < 2; ++mi)
        #pragma unroll
        for (int ni = 0; ni < 4; ++ni) acc[mi][ni] = (f32x4){0.f, 0.f, 0.f, 0.f};

    // A super stage: round q -> row = q*8 + wid (wave-uniform), lane covers
    // the row's 64 16B-chunks; src chunk pre-swizzled by ^(row&7).
    auto stageA = [&](int k0) {
        #pragma unroll
        for (int q = 0; q < 8; ++q) {
            const int row = q * 8 + wid;
            const int sc = lane ^ (row & 7);
            gload16(&x[(size_t)(i0 + row) * T_LEN + k0 + sc * 4],
                    (char*)Asf + row * 1024);
        }
    };
    // B stage: round q -> 8 rows x 128 B per wave-instr (L2-resident slice).
    auto stageB = [&](int k0) {
        #pragma unroll
        for (int q = 0; q < 4; ++q) {
            const int rowb = q * 64 + wid * 8 + (lane >> 3);
            const int sc = (lane & 7) ^ (rowb & 7);
            gload16(&zbf[(size_t)rowb * T_LEN + k0 + sc * 8],
                    (char*)Bs + (q * 64 + wid * 8) * 128);
        }
    };

    const int nsup = klen / SUPK;         // 4
    for (int s = 0; s < nsup; ++s) {
        const int k0 = kbase + s * SUPK;
        stageA(k0);                       // 1 KB contiguous per row
        #pragma unroll
        for (int inner = 0; inner < 4; ++inner) {
            stageB(k0 + inner * GBK);
            __syncthreads();              // drain DMAs: tile visible
            #pragma unroll
            for (int ksb = 0; ksb < 2; ++ksb) {
                short8 af[2], bfr[4];
                #pragma unroll
                for (int mi = 0; mi < 2; ++mi) {
                    const int row = wm * 32 + mi * 16 + l15;
                    const int c0 = inner * 16 + lg * 2 + ksb * 8;  // 16B chunks
                    const f32x4 v0 = *(const f32x4*)((const char*)Asf + row * 1024
                                                     + ((c0 ^ (row & 7)) * 16));
                    const f32x4 v1 = *(const f32x4*)((const char*)Asf + row * 1024
                                                     + (((c0 + 1) ^ (row & 7)) * 16));
                    short8 f;
                    f[0] = (short)f2bf(v0[0]); f[1] = (short)f2bf(v0[1]);
                    f[2] = (short)f2bf(v0[2]); f[3] = (short)f2bf(v0[3]);
                    f[4] = (short)f2bf(v1[0]); f[5] = (short)f2bf(v1[1]);
                    f[6] = (short)f2bf(v1[2]); f[7] = (short)f2bf(v1[3]);
                    af[mi] = f;
                }
                #pragma unroll
                for (int ni = 0; ni < 4; ++ni) {
                    const int row = wn * 64 + ni * 16 + l15;
                    const int c = lg + ksb * 4;
                    bfr[ni] = *(const short8*)((const char*)Bs + row * 128
                                               + ((c ^ (row & 7)) * 16));
                }
                #pragma unroll
                for (int mi = 0; mi < 2; ++mi)
                    #pragma unroll
                    for (int ni = 0; ni < 4; ++ni)
                        acc[mi][ni] = __builtin_amdgcn_mfma_f32_16x16x32_bf16(
                            af[mi], bfr[ni], acc[mi][ni], 0, 0, 0);
            }
            __syncthreads();              // all reads done before next overwrite
        }
    }

    // C/D layout: col = lane&15, row = (lane>>4)*4 + reg
    #pragma unroll
    for (int mi = 0; mi < 2; ++mi) {
        #pragma unroll
        for (int ni = 0; ni < 4; ++ni) {
            const int gn = wn * 64 + ni * 16 + l15;
            #pragma unroll
            for (int rg = 0; rg < 4; ++rg) {
                const int gm = i0 + wm * 32 + mi * 16 + lg * 4 + rg;
                part[((size_t)ks * B_ROWS + gm) * N_TAPS + gn] = acc[mi][ni][rg];
            }
        }
    }
}

// ---------------------------------------------------------------------------
// Phase 2: reduce split-K partials -> zi
// ---------------------------------------------------------------------------
__global__ __launch_bounds__(256) void fir_zi_reduce(const float* __restrict__ part,
                                                     float* __restrict__ zi,
                                                     int kslices) {
    const int idx = blockIdx.x * 256 + threadIdx.x;
    const int total = B_ROWS * N_TAPS / 4;
    if (idx >= total) return;
    float4 s = ((const float4*)part)[idx];
    for (int q = 1; q < kslices; ++q) {
        float4 v = ((const float4*)part)[(size_t)q * total + idx];
        s.x += v.x; s.y += v.y; s.z += v.z; s.w += v.w;
    }
    ((float4*)zi)[idx] = s;
}

// ---------------------------------------------------------------------------
// Phase 3: FIR conv via MFMA (unchanged from R3 — verified)
// ---------------------------------------------------------------------------
#define VBM 16
#define VBT 1024
#define VWIN 1280
#define VSTR 2560

__global__ __launch_bounds__(256, 2) void fir_conv_mfma(
        const float* __restrict__ x,
        const ushort* __restrict__ wtab,
        const float* __restrict__ zi,
        float* __restrict__ y) {
    __shared__ ushort xe[VBM * VSTR / 2];
    const int t0 = blockIdx.x * VBT;
    const int i0 = blockIdx.y * VBM;
    const int tid = threadIdx.x;
    const int lane = tid & 63, wid = tid >> 6;
    const int l15 = lane & 15, lg = lane >> 4;

    short8 wf[18];
    #pragma unroll
    for (int a = 0; a < 18; ++a)
        wf[a] = *(const short8*)&wtab[((a + 2) * 64 + lane) * 8];

    #pragma unroll
    for (int it = 0; it < 8; ++it) {
        const int e = tid + it * 256;
        const int r = e >> 7;
        const int c8 = e & 127;
        const int g = t0 + c8 * 8;
        float4 v0 = *(const float4*)&x[(size_t)(i0 + r) * T_LEN + g];
        float4 v1 = *(const float4*)&x[(size_t)(i0 + r) * T_LEN + g + 4];
        short8 o;
        o[0] = (short)f2bf(v0.x); o[1] = (short)f2bf(v0.y);
        o[2] = (short)f2bf(v0.z); o[3] = (short)f2bf(v0.w);
        o[4] = (short)f2bf(v1.x); o[5] = (short)f2bf(v1.y);
        o[6] = (short)f2bf(v1.z); o[7] = (short)f2bf(v1.w);
        const int off = (512 + c8 * 16) ^ ((r & 7) << 4);
        *(short8*)((char*)xe + r * VSTR + off) = o;
    }
    #pragma unroll
    for (int it = 0; it < 2; ++it) {
        const int e = tid + it * 256;
        const int r = e >> 5;
        const int c8 = e & 31;
        const int g = t0 - 256 + c8 * 8;
        short8 o;
        if (g >= 0) {
            float4 v0 = *(const float4*)&x[(size_t)(i0 + r) * T_LEN + g];
            float4 v1 = *(const float4*)&x[(size_t)(i0 + r) * T_LEN + g + 4];
            o[0] = (short)f2bf(v0.x); o[1] = (short)f2bf(v0.y);
            o[2] = (short)f2bf(v0.z); o[3] = (short)f2bf(v0.w);
            o[4] = (short)f2bf(v1.x); o[5] = (short)f2bf(v1.y);
            o[6] = (short)f2bf(v1.z); o[7] = (short)f2bf(v1.w);
        } else {
            #pragma unroll
            for (int jj = 0; jj < 8; ++jj)
                o[jj] = (short)f2bf(zi[(size_t)(i0 + r) * N_TAPS + (-1 - g - jj)]);
        }
        const int off = (c8 * 16) ^ ((r & 7) << 4);
        *(short8*)((char*)xe + r * VSTR + off) = o;
    }
    __syncthreads();

    f32x4 acc[4][4];
    #pragma unroll
    for (int c4 = 0; c4 < 4; ++c4)
        #pragma unroll
        for (int n = 0; n < 4; ++n) acc[c4][n] = (f32x4){0.f, 0.f, 0.f, 0.f};

    const int chunk0 = wid * 4;
    #pragma unroll
    for (int ui = 0; ui < 10; ++ui) {
        #pragma unroll
        for (int c4 = 0; c4 < 4; ++c4) {
            const int colw = (chunk0 + c4) * 64 + ui * 32 + lg * 8;
            const int off = (colw * 2) ^ ((l15 & 7) << 4);
            short8 af = *(const short8*)((const char*)xe + l15 * VSTR + off);
            #pragma unroll
            for (int ncol = 0; ncol < 4; ++ncol) {
                const int a = ncol + 18 - 2 * ui;
                if (a >= 2 && a <= 19)
                    acc[c4][ncol] = __builtin_amdgcn_mfma_f32_16x16x32_bf16(
                        af, wf[a - 2], acc[c4][ncol], 0, 0, 0);
            }
        }
    }

    #pragma unroll
    for (int c4 = 0; c4 < 4; ++c4) {
        #pragma unroll
        for (int ncol = 0; ncol < 4; ++ncol) {
            const size_t tcol = (size_t)t0 + (chunk0 + c4) * 64 + ncol * 16 + l15;
            #pragma unroll
            for (int rg = 0; rg < 4; ++rg) {
                y[(size_t)(i0 + lg * 4 + rg) * T_LEN + tcol] = acc[c4][ncol][rg];
            }
        }
    }
}

// ---------------------------------------------------------------------------
extern "C" void kernel_launch(void* const* d_in, const int* in_sizes, int n_in,
                              void* d_out, int out_size, void* d_ws, size_t ws_size,
                              hipStream_t stream) {
    const float* x  = (const float*)d_in[0];
    const float* b  = (const float*)d_in[1];
    const float* z  = (const float*)d_in[2];
    float* y = (float*)d_out;

    char* ws = (char*)d_ws;
    float*  zi   = (float*)ws;                            // 4 MB
    ushort* zbf  = (ushort*)(ws + (4u << 20));            // 4 MB
    ushort* wtab = (ushort*)(ws + (8u << 20));            // 22.5 KB (reserve 64K)
    float*  part = (float*)(ws + (8u << 20) + (64u << 10));

    int kslices = 8;
    while (kslices > 1 &&
           (size_t)(8u << 20) + (64u << 10) + (size_t)kslices * (4u << 20) > ws_size)
        kslices >>= 1;

    fir_build_wtab<<<22, 64, 0, stream>>>(b, wtab);
    fir_cast_z<<<N_TAPS * T_LEN / (256 * 8), 256, 0, stream>>>(z, zbf);

    dim3 ggrid(B_ROWS / MT, kslices);                     // 64 x 8 = 512 blocks
    fir_zi_gemm<<<ggrid, 512, 0, stream>>>(x, zbf, part, kslices);

    fir_zi_reduce<<<B_ROWS * N_TAPS / 4 / 256, 256, 0, stream>>>(part, zi, kslices);

    dim3 cgrid(T_LEN / VBT, B_ROWS / VBM);                // 8 x 256
    fir_conv_mfma<<<cgrid, 256, 0, stream>>>(x, wtab, zi, y);
}